// Round 4
// baseline (41507.175 us; speedup 1.0000x reference)
//
#include <hip/hip_runtime.h>
#include <math.h>

// ws layout (float offsets)
#define OFF_WIT   0          // WiT[k][j]  : 128 x 512
#define OFF_WHT   65536      // WhT[k][j]  : 128 x 512
#define OFF_GWQT  131072     // gWqT[k][o] : 128 x 128
#define OFF_PWQT  147456
#define OFF_GWRT  163840     // gWrefT[k][o]
#define OFF_PWRT  180224     // pWrefT[k][o]
#define OFF_EG    196608ull            // eg slabs: 1024 x 12800
#define OFF_EP    (196608ull + 13107200ull)  // ep slabs: 1024 x 12800

// out layout (float offsets): probs(100,1024,100), sels(100,1024), hx(1024,128), cx(1024,128)
#define OUT_PROBS 0
#define OUT_SELS  10240000
#define OUT_HX    10342400
#define OUT_CX    10473472

__global__ __launch_bounds__(256) void transpose_k(
    const float* __restrict__ Wi, const float* __restrict__ Wh,
    const float* __restrict__ gWq, const float* __restrict__ pWq,
    const float* __restrict__ gWr, const float* __restrict__ pWr,
    float* __restrict__ ws) {
  int idx = blockIdx.x * 256 + threadIdx.x;   // < 65536
  int k9 = idx >> 9, j = idx & 511;
  ws[OFF_WIT + idx] = Wi[j * 128 + k9];
  ws[OFF_WHT + idx] = Wh[j * 128 + k9];
  if (idx < 16384) {
    int k = idx >> 7, o = idx & 127;
    ws[OFF_GWQT + idx] = gWq[o * 128 + k];
    ws[OFF_PWQT + idx] = pWq[o * 128 + k];
    ws[OFF_GWRT + idx] = gWr[o * 128 + k];
    ws[OFF_PWRT + idx] = pWr[o * 128 + k];
  }
}

// ---------------------------------------------------------------------------
// FAST PATH: identical FP code to the round-1 (passing) kernel; only eg/ep
// live in global ws instead of LDS. LDS ~10KB -> ~3 blocks/CU instead of 1.
// ---------------------------------------------------------------------------
__global__ __launch_bounds__(256) void decoder_fast(
    const float* __restrict__ dec, const float* __restrict__ emb,
    const float* __restrict__ h0, const float* __restrict__ c0,
    const float* __restrict__ ctx,
    const float* __restrict__ bi, const float* __restrict__ bh,
    const float* __restrict__ gbq, const float* __restrict__ gv,
    const float* __restrict__ pbq, const float* __restrict__ pv,
    const float* __restrict__ gbr, const float* __restrict__ pbr,
    const float* __restrict__ ws, float* __restrict__ egs, float* __restrict__ eps,
    float* __restrict__ out) {
  __shared__ float xv[128], hv[128], cv[128];
  __shared__ float gates[512];
  __shared__ float qv[128], glv[128];
  __shared__ float uu[112], aa[112], lgt[112], prb[112];
  __shared__ float ctxtile[800];  // 8 k x 100 s
  __shared__ int maskI[112];
  __shared__ int selIdx;

  const int tid = threadIdx.x;
  const int lane = tid & 63;
  const int wid = tid >> 6;
  const int b = blockIdx.x;

  float* __restrict__ eg = egs + (size_t)b * 12800;
  float* __restrict__ ep = eps + (size_t)b * 12800;

  // ---------- compute e_g / e_p slabs for this b (R1-verbatim chains) ----------
  {
    const int h = tid & 127;
    const int shalf = tid >> 7;  // 0 or 1 -> s in [shalf*50, shalf*50+50)
    const float* gWrT = ws + OFF_GWRT;
    const float* pWrT = ws + OFF_PWRT;
    float ag[50], ap[50];
    const float bgv = gbr[h], bpv = pbr[h];
#pragma unroll
    for (int i = 0; i < 50; i++) { ag[i] = bgv; ap[i] = bpv; }
    for (int kb = 0; kb < 128; kb += 8) {
      __syncthreads();
      for (int idx = tid; idx < 800; idx += 256) {
        int kk = idx / 100;
        int s = idx - kk * 100;
        ctxtile[idx] = ctx[((size_t)(s * 128 + kb + kk)) * 1024 + b];
      }
      __syncthreads();
      for (int kk = 0; kk < 8; kk++) {
        int k = kb + kk;
        float wg = gWrT[k * 128 + h];
        float wp = pWrT[k * 128 + h];
        const float* cc = ctxtile + kk * 100 + shalf * 50;
#pragma unroll
        for (int i = 0; i < 50; i++) {
          float cva = cc[i];
          ag[i] += wg * cva;
          ap[i] += wp * cva;
        }
      }
    }
#pragma unroll
    for (int i = 0; i < 50; i++) {
      int s = shalf * 50 + i;
      eg[s * 128 + h] = ag[i];
      ep[s * 128 + h] = ap[i];
    }
  }

  // ---------- init state ----------
  if (tid < 128) {
    xv[tid] = dec[b * 128 + tid];
    hv[tid] = h0[b * 128 + tid];
    cv[tid] = c0[b * 128 + tid];
  }
  if (tid < 112) maskI[tid] = 0;
  const float base0 = bi[2 * tid] + bh[2 * tid];
  const float base1 = bi[2 * tid + 1] + bh[2 * tid + 1];
  const float gv0 = gv[lane], gv1 = gv[lane + 64];
  const float pv0 = pv[lane], pv1 = pv[lane + 64];
  const float2* Wi2 = (const float2*)(ws + OFF_WIT);
  const float2* Wh2 = (const float2*)(ws + OFF_WHT);
  const float* gWqT = ws + OFF_GWQT;
  const float* pWqT = ws + OFF_PWQT;
  __syncthreads();

  for (int t = 0; t < 100; t++) {
    // ---- stage 1: gates = x@Wi.T + bi + h@Wh.T + bh (j = 2*tid, 2*tid+1) ----
    float a0 = base0, a1 = base1;
    for (int k = 0; k < 128; k++) {
      float xk = xv[k], hk = hv[k];
      float2 wi = Wi2[k * 256 + tid];
      float2 wh = Wh2[k * 256 + tid];
      a0 += wi.x * xk + wh.x * hk;
      a1 += wi.y * xk + wh.y * hk;
    }
    gates[2 * tid] = a0;
    gates[2 * tid + 1] = a1;
    __syncthreads();

    // ---- stage 2: LSTM cell ----
    if (tid < 128) {
      float ii = 1.f / (1.f + expf(-gates[tid]));
      float ff = 1.f / (1.f + expf(-gates[128 + tid]));
      float gg = tanhf(gates[256 + tid]);
      float oo = 1.f / (1.f + expf(-gates[384 + tid]));
      float cy = ff * cv[tid] + ii * gg;
      float hy = oo * tanhf(cy);
      cv[tid] = cy;
      hv[tid] = hy;
    }
    __syncthreads();

    // ---- stage 3: q = hy @ gWq.T + gbq ----
    if (tid < 128) {
      float acc = gbq[tid];
      for (int k = 0; k < 128; k++) acc += gWqT[k * 128 + tid] * hv[k];
      qv[tid] = acc;
    }
    __syncthreads();

    // ---- stage 4: u_g[s] = sum_h gv[h] * tanh(q[h] + eg[s][h]), masked ----
    for (int s = wid; s < 100; s += 4) {
      float t0 = tanhf(qv[lane] + eg[s * 128 + lane]);
      float t1 = tanhf(qv[lane + 64] + eg[s * 128 + lane + 64]);
      float part = gv0 * t0 + gv1 * t1;
#pragma unroll
      for (int off = 32; off >= 1; off >>= 1) part += __shfl_xor(part, off);
      if (lane == 0) uu[s] = maskI[s] ? -INFINITY : part;
    }
    __syncthreads();

    // ---- stage 5: softmax over uu -> aa ----
    if (wid == 0) {
      float v0 = (lane < 100) ? uu[lane] : -INFINITY;
      float v1 = (lane < 36) ? uu[lane + 64] : -INFINITY;
      float m = fmaxf(v0, v1);
#pragma unroll
      for (int off = 32; off >= 1; off >>= 1) m = fmaxf(m, __shfl_xor(m, off));
      float e0 = (lane < 100) ? expf(v0 - m) : 0.f;
      float e1 = (lane < 36) ? expf(v1 - m) : 0.f;
      float ssum = e0 + e1;
#pragma unroll
      for (int off = 32; off >= 1; off >>= 1) ssum += __shfl_xor(ssum, off);
      if (lane < 100) aa[lane] = e0 / ssum;
      if (lane < 36) aa[lane + 64] = e1 / ssum;
    }
    __syncthreads();

    // ---- stage 6: gl[h] = sum_s eg[s][h] * aa[s] ----
    if (tid < 128) {
      float acc = 0.f;
      for (int s = 0; s < 100; s++) acc += aa[s] * eg[s * 128 + tid];
      glv[tid] = acc;
    }
    __syncthreads();

    // ---- stage 7: q2 = gl @ pWq.T + pbq ----
    if (tid < 128) {
      float acc = pbq[tid];
      for (int k = 0; k < 128; k++) acc += pWqT[k * 128 + tid] * glv[k];
      qv[tid] = acc;
    }
    __syncthreads();

    // ---- stage 8: logits ----
    for (int s = wid; s < 100; s += 4) {
      float t0 = tanhf(qv[lane] + ep[s * 128 + lane]);
      float t1 = tanhf(qv[lane + 64] + ep[s * 128 + lane + 64]);
      float part = pv0 * t0 + pv1 * t1;
#pragma unroll
      for (int off = 32; off >= 1; off >>= 1) part += __shfl_xor(part, off);
      if (lane == 0) lgt[s] = maskI[s] ? -INFINITY : 10.f * tanhf(part);
    }
    __syncthreads();

    // ---- stage 9: softmax -> probs, argmax (first max) ----
    if (wid == 0) {
      float v0 = (lane < 100) ? lgt[lane] : -INFINITY;
      float v1 = (lane < 36) ? lgt[lane + 64] : -INFINITY;
      float m = fmaxf(v0, v1);
#pragma unroll
      for (int off = 32; off >= 1; off >>= 1) m = fmaxf(m, __shfl_xor(m, off));
      float e0 = (lane < 100) ? expf(v0 - m) : 0.f;
      float e1 = (lane < 36) ? expf(v1 - m) : 0.f;
      float ssum = e0 + e1;
#pragma unroll
      for (int off = 32; off >= 1; off >>= 1) ssum += __shfl_xor(ssum, off);
      float p0 = e0 / ssum;
      float p1 = e1 / ssum;
      if (lane < 100) prb[lane] = p0;
      if (lane < 36) prb[lane + 64] = p1;
      float bp;
      int bs;
      if (lane < 100) { bp = p0; bs = lane; } else { bp = -1.f; bs = 1 << 20; }
      if (lane < 36 && p1 > bp) { bp = p1; bs = lane + 64; }
#pragma unroll
      for (int off = 32; off >= 1; off >>= 1) {
        float op = __shfl_xor(bp, off);
        int os = __shfl_xor(bs, off);
        if (op > bp || (op == bp && os < bs)) { bp = op; bs = os; }
      }
      if (lane == 0) {
        selIdx = bs;
        out[OUT_SELS + t * 1024 + b] = (float)bs;
      }
    }
    __syncthreads();

    // ---- stage 10: write probs, gather next input, update mask ----
    if (tid < 100) out[OUT_PROBS + (size_t)t * 102400 + b * 100 + tid] = prb[tid];
    int idx = selIdx;
    if (tid < 128) xv[tid] = emb[((size_t)(idx * 1024 + b)) * 128 + tid];
    if (tid == 0) maskI[idx] = 1;
    __syncthreads();
  }

  if (tid < 128) {
    out[OUT_HX + b * 128 + tid] = hv[tid];
    out[OUT_CX + b * 128 + tid] = cv[tid];
  }
}

// ---------------------------------------------------------------------------
// FALLBACK: round-1 kernel verbatim (eg/ep in LDS), used if ws is too small.
// ---------------------------------------------------------------------------
__global__ __launch_bounds__(256) void decoder_lds(
    const float* __restrict__ dec, const float* __restrict__ emb,
    const float* __restrict__ h0, const float* __restrict__ c0,
    const float* __restrict__ ctx,
    const float* __restrict__ bi, const float* __restrict__ bh,
    const float* __restrict__ gbq, const float* __restrict__ gv,
    const float* __restrict__ pbq, const float* __restrict__ pv,
    const float* __restrict__ gbr, const float* __restrict__ pbr,
    const float* __restrict__ ws, float* __restrict__ out) {
  __shared__ float eg[12800];
  __shared__ float ep[12800];
  __shared__ float xv[128], hv[128], cv[128];
  __shared__ float gates[512];
  __shared__ float qv[128], glv[128];
  __shared__ float uu[112], aa[112], lgt[112], prb[112];
  __shared__ float ctxtile[800];
  __shared__ int maskI[112];
  __shared__ int selIdx;

  const int tid = threadIdx.x;
  const int lane = tid & 63;
  const int wid = tid >> 6;
  const int b = blockIdx.x;

  {
    const int h = tid & 127;
    const int shalf = tid >> 7;
    const float* gWrT = ws + OFF_GWRT;
    const float* pWrT = ws + OFF_PWRT;
    float ag[50], ap[50];
    const float bgv = gbr[h], bpv = pbr[h];
#pragma unroll
    for (int i = 0; i < 50; i++) { ag[i] = bgv; ap[i] = bpv; }
    for (int kb = 0; kb < 128; kb += 8) {
      __syncthreads();
      for (int idx = tid; idx < 800; idx += 256) {
        int kk = idx / 100;
        int s = idx - kk * 100;
        ctxtile[idx] = ctx[((size_t)(s * 128 + kb + kk)) * 1024 + b];
      }
      __syncthreads();
      for (int kk = 0; kk < 8; kk++) {
        int k = kb + kk;
        float wg = gWrT[k * 128 + h];
        float wp = pWrT[k * 128 + h];
        const float* cc = ctxtile + kk * 100 + shalf * 50;
#pragma unroll
        for (int i = 0; i < 50; i++) {
          float cva = cc[i];
          ag[i] += wg * cva;
          ap[i] += wp * cva;
        }
      }
    }
#pragma unroll
    for (int i = 0; i < 50; i++) {
      int s = shalf * 50 + i;
      eg[s * 128 + h] = ag[i];
      ep[s * 128 + h] = ap[i];
    }
  }

  if (tid < 128) {
    xv[tid] = dec[b * 128 + tid];
    hv[tid] = h0[b * 128 + tid];
    cv[tid] = c0[b * 128 + tid];
  }
  if (tid < 112) maskI[tid] = 0;
  const float base0 = bi[2 * tid] + bh[2 * tid];
  const float base1 = bi[2 * tid + 1] + bh[2 * tid + 1];
  const float gv0 = gv[lane], gv1 = gv[lane + 64];
  const float pv0 = pv[lane], pv1 = pv[lane + 64];
  const float2* Wi2 = (const float2*)(ws + OFF_WIT);
  const float2* Wh2 = (const float2*)(ws + OFF_WHT);
  const float* gWqT = ws + OFF_GWQT;
  const float* pWqT = ws + OFF_PWQT;
  __syncthreads();

  for (int t = 0; t < 100; t++) {
    float a0 = base0, a1 = base1;
    for (int k = 0; k < 128; k++) {
      float xk = xv[k], hk = hv[k];
      float2 wi = Wi2[k * 256 + tid];
      float2 wh = Wh2[k * 256 + tid];
      a0 += wi.x * xk + wh.x * hk;
      a1 += wi.y * xk + wh.y * hk;
    }
    gates[2 * tid] = a0;
    gates[2 * tid + 1] = a1;
    __syncthreads();

    if (tid < 128) {
      float ii = 1.f / (1.f + expf(-gates[tid]));
      float ff = 1.f / (1.f + expf(-gates[128 + tid]));
      float gg = tanhf(gates[256 + tid]);
      float oo = 1.f / (1.f + expf(-gates[384 + tid]));
      float cy = ff * cv[tid] + ii * gg;
      float hy = oo * tanhf(cy);
      cv[tid] = cy;
      hv[tid] = hy;
    }
    __syncthreads();

    if (tid < 128) {
      float acc = gbq[tid];
      for (int k = 0; k < 128; k++) acc += gWqT[k * 128 + tid] * hv[k];
      qv[tid] = acc;
    }
    __syncthreads();

    for (int s = wid; s < 100; s += 4) {
      float t0 = tanhf(qv[lane] + eg[s * 128 + lane]);
      float t1 = tanhf(qv[lane + 64] + eg[s * 128 + lane + 64]);
      float part = gv0 * t0 + gv1 * t1;
#pragma unroll
      for (int off = 32; off >= 1; off >>= 1) part += __shfl_xor(part, off);
      if (lane == 0) uu[s] = maskI[s] ? -INFINITY : part;
    }
    __syncthreads();

    if (wid == 0) {
      float v0 = (lane < 100) ? uu[lane] : -INFINITY;
      float v1 = (lane < 36) ? uu[lane + 64] : -INFINITY;
      float m = fmaxf(v0, v1);
#pragma unroll
      for (int off = 32; off >= 1; off >>= 1) m = fmaxf(m, __shfl_xor(m, off));
      float e0 = (lane < 100) ? expf(v0 - m) : 0.f;
      float e1 = (lane < 36) ? expf(v1 - m) : 0.f;
      float ssum = e0 + e1;
#pragma unroll
      for (int off = 32; off >= 1; off >>= 1) ssum += __shfl_xor(ssum, off);
      if (lane < 100) aa[lane] = e0 / ssum;
      if (lane < 36) aa[lane + 64] = e1 / ssum;
    }
    __syncthreads();

    if (tid < 128) {
      float acc = 0.f;
      for (int s = 0; s < 100; s++) acc += aa[s] * eg[s * 128 + tid];
      glv[tid] = acc;
    }
    __syncthreads();

    if (tid < 128) {
      float acc = pbq[tid];
      for (int k = 0; k < 128; k++) acc += pWqT[k * 128 + tid] * glv[k];
      qv[tid] = acc;
    }
    __syncthreads();

    for (int s = wid; s < 100; s += 4) {
      float t0 = tanhf(qv[lane] + ep[s * 128 + lane]);
      float t1 = tanhf(qv[lane + 64] + ep[s * 128 + lane + 64]);
      float part = pv0 * t0 + pv1 * t1;
#pragma unroll
      for (int off = 32; off >= 1; off >>= 1) part += __shfl_xor(part, off);
      if (lane == 0) lgt[s] = maskI[s] ? -INFINITY : 10.f * tanhf(part);
    }
    __syncthreads();

    if (wid == 0) {
      float v0 = (lane < 100) ? lgt[lane] : -INFINITY;
      float v1 = (lane < 36) ? lgt[lane + 64] : -INFINITY;
      float m = fmaxf(v0, v1);
#pragma unroll
      for (int off = 32; off >= 1; off >>= 1) m = fmaxf(m, __shfl_xor(m, off));
      float e0 = (lane < 100) ? expf(v0 - m) : 0.f;
      float e1 = (lane < 36) ? expf(v1 - m) : 0.f;
      float ssum = e0 + e1;
#pragma unroll
      for (int off = 32; off >= 1; off >>= 1) ssum += __shfl_xor(ssum, off);
      float p0 = e0 / ssum;
      float p1 = e1 / ssum;
      if (lane < 100) prb[lane] = p0;
      if (lane < 36) prb[lane + 64] = p1;
      float bp;
      int bs;
      if (lane < 100) { bp = p0; bs = lane; } else { bp = -1.f; bs = 1 << 20; }
      if (lane < 36 && p1 > bp) { bp = p1; bs = lane + 64; }
#pragma unroll
      for (int off = 32; off >= 1; off >>= 1) {
        float op = __shfl_xor(bp, off);
        int os = __shfl_xor(bs, off);
        if (op > bp || (op == bp && os < bs)) { bp = op; bs = os; }
      }
      if (lane == 0) {
        selIdx = bs;
        out[OUT_SELS + t * 1024 + b] = (float)bs;
      }
    }
    __syncthreads();

    if (tid < 100) out[OUT_PROBS + (size_t)t * 102400 + b * 100 + tid] = prb[tid];
    int idx = selIdx;
    if (tid < 128) xv[tid] = emb[((size_t)(idx * 1024 + b)) * 128 + tid];
    if (tid == 0) maskI[idx] = 1;
    __syncthreads();
  }

  if (tid < 128) {
    out[OUT_HX + b * 128 + tid] = hv[tid];
    out[OUT_CX + b * 128 + tid] = cv[tid];
  }
}

extern "C" void kernel_launch(void* const* d_in, const int* in_sizes, int n_in,
                              void* d_out, int out_size, void* d_ws, size_t ws_size,
                              hipStream_t stream) {
  (void)in_sizes; (void)n_in; (void)out_size;
  const float* dec = (const float*)d_in[0];
  const float* emb = (const float*)d_in[1];
  const float* h0  = (const float*)d_in[2];
  const float* c0  = (const float*)d_in[3];
  const float* ctx = (const float*)d_in[4];
  const float* Wi  = (const float*)d_in[5];
  const float* bi  = (const float*)d_in[6];
  const float* Wh  = (const float*)d_in[7];
  const float* bh  = (const float*)d_in[8];
  const float* gWq = (const float*)d_in[9];
  const float* gbq = (const float*)d_in[10];
  const float* gWr = (const float*)d_in[11];
  const float* gbr = (const float*)d_in[12];
  const float* gv  = (const float*)d_in[13];
  const float* pWq = (const float*)d_in[14];
  const float* pbq = (const float*)d_in[15];
  const float* pWr = (const float*)d_in[16];
  const float* pbr = (const float*)d_in[17];
  const float* pv  = (const float*)d_in[18];
  float* ws = (float*)d_ws;
  float* out = (float*)d_out;

  hipLaunchKernelGGL(transpose_k, dim3(256), dim3(256), 0, stream,
                     Wi, Wh, gWq, pWq, gWr, pWr, ws);

  const size_t need_bytes = (size_t)(OFF_EP + 13107200ull) * 4ull;  // ~105.6 MB
  if (ws_size >= need_bytes) {
    float* egs = ws + OFF_EG;
    float* eps = ws + OFF_EP;
    hipLaunchKernelGGL(decoder_fast, dim3(1024), dim3(256), 0, stream,
                       dec, emb, h0, c0, ctx, bi, bh, gbq, gv, pbq, pv, gbr, pbr,
                       ws, egs, eps, out);
  } else {
    hipLaunchKernelGGL(decoder_lds, dim3(1024), dim3(256), 0, stream,
                       dec, emb, h0, c0, ctx, bi, bh, gbq, gv, pbq, pv, gbr, pbr,
                       ws, out);
  }
}

// Round 5
// 10340.056 us; speedup vs baseline: 4.0142x; 4.0142x over previous
//
#include <hip/hip_runtime.h>
#include <math.h>

// ws layout (float offsets)
#define OFF_WIT   0          // WiT[k][j]  : 128 x 512
#define OFF_WHT   65536      // WhT[k][j]  : 128 x 512
#define OFF_GWQT  131072     // gWqT[k][o] : 128 x 128
#define OFF_PWQT  147456
#define OFF_GWRT  163840     // gWrefT[k][o]
#define OFF_PWRT  180224     // pWrefT[k][o]
#define OFF_EG    196608ull            // eg slabs: 1024 x 12800
#define OFF_EP    (196608ull + 13107200ull)  // ep slabs: 1024 x 12800

// out layout (float offsets): probs(100,1024,100), sels(100,1024), hx(1024,128), cx(1024,128)
#define OUT_PROBS 0
#define OUT_SELS  10240000
#define OUT_HX    10342400
#define OUT_CX    10473472

__global__ __launch_bounds__(256) void transpose_k(
    const float* __restrict__ Wi, const float* __restrict__ Wh,
    const float* __restrict__ gWq, const float* __restrict__ pWq,
    const float* __restrict__ gWr, const float* __restrict__ pWr,
    float* __restrict__ ws) {
  int idx = blockIdx.x * 256 + threadIdx.x;   // < 65536
  int k9 = idx >> 9, j = idx & 511;
  ws[OFF_WIT + idx] = Wi[j * 128 + k9];
  ws[OFF_WHT + idx] = Wh[j * 128 + k9];
  if (idx < 16384) {
    int k = idx >> 7, o = idx & 127;
    ws[OFF_GWQT + idx] = gWq[o * 128 + k];
    ws[OFF_PWQT + idx] = pWq[o * 128 + k];
    ws[OFF_GWRT + idx] = gWr[o * 128 + k];
    ws[OFF_PWRT + idx] = pWr[o * 128 + k];
  }
}

// ---------------------------------------------------------------------------
// Precompute kernel: R1/R4's e-slab computation verbatim, one block per b,
// writing both slabs to global ws (exact R4 pattern — bit-proven).
// Register arrays / any scratch live only here, not in the decoder.
// ---------------------------------------------------------------------------
__global__ __launch_bounds__(256) void precompute_e(
    const float* __restrict__ ctx,
    const float* __restrict__ gbr, const float* __restrict__ pbr,
    const float* __restrict__ ws,
    float* __restrict__ egs, float* __restrict__ eps) {
  __shared__ float ctxtile[800];  // 8 k x 100 s
  const int tid = threadIdx.x;
  const int b = blockIdx.x;
  float* __restrict__ eg = egs + (size_t)b * 12800;
  float* __restrict__ ep = eps + (size_t)b * 12800;

  const int h = tid & 127;
  const int shalf = tid >> 7;  // 0 or 1 -> s in [shalf*50, shalf*50+50)
  const float* gWrT = ws + OFF_GWRT;
  const float* pWrT = ws + OFF_PWRT;
  float ag[50], ap[50];
  const float bgv = gbr[h], bpv = pbr[h];
#pragma unroll
  for (int i = 0; i < 50; i++) { ag[i] = bgv; ap[i] = bpv; }
  for (int kb = 0; kb < 128; kb += 8) {
    __syncthreads();
    for (int idx = tid; idx < 800; idx += 256) {
      int kk = idx / 100;
      int s = idx - kk * 100;
      ctxtile[idx] = ctx[((size_t)(s * 128 + kb + kk)) * 1024 + b];
    }
    __syncthreads();
    for (int kk = 0; kk < 8; kk++) {
      int k = kb + kk;
      float wg = gWrT[k * 128 + h];
      float wp = pWrT[k * 128 + h];
      const float* cc = ctxtile + kk * 100 + shalf * 50;
#pragma unroll
      for (int i = 0; i < 50; i++) {
        float cva = cc[i];
        ag[i] += wg * cva;
        ap[i] += wp * cva;
      }
    }
  }
#pragma unroll
  for (int i = 0; i < 50; i++) {
    int s = shalf * 50 + i;
    eg[s * 128 + h] = ag[i];
    ep[s * 128 + h] = ap[i];
  }
}

// ---------------------------------------------------------------------------
// Decoder: R1 stage text verbatim. eg staged global->LDS (bitwise copy),
// ep read from global (R4-proven stage-8 text). LDS ~58KB -> 2 blocks/CU.
// ---------------------------------------------------------------------------
__global__ __launch_bounds__(256) void decoder_fast(
    const float* __restrict__ dec, const float* __restrict__ emb,
    const float* __restrict__ h0, const float* __restrict__ c0,
    const float* __restrict__ bi, const float* __restrict__ bh,
    const float* __restrict__ gbq, const float* __restrict__ gv,
    const float* __restrict__ pbq, const float* __restrict__ pv,
    const float* __restrict__ ws,
    const float* __restrict__ egs, const float* __restrict__ eps,
    float* __restrict__ out) {
  __shared__ float eg[12800];   // [s][h] for this b
  __shared__ float xv[128], hv[128], cv[128];
  __shared__ float gates[512];
  __shared__ float qv[128], glv[128];
  __shared__ float uu[112], aa[112], lgt[112], prb[112];
  __shared__ int maskI[112];
  __shared__ int selIdx;

  const int tid = threadIdx.x;
  const int lane = tid & 63;
  const int wid = tid >> 6;
  const int b = blockIdx.x;

  const float* __restrict__ ep = eps + (size_t)b * 12800;

  // ---------- stage eg slab into LDS (pure bitwise copy) ----------
  {
    const float4* src = (const float4*)(egs + (size_t)b * 12800);
    float4* dst = (float4*)eg;
    for (int i = tid; i < 3200; i += 256) dst[i] = src[i];
  }

  // ---------- init state ----------
  if (tid < 128) {
    xv[tid] = dec[b * 128 + tid];
    hv[tid] = h0[b * 128 + tid];
    cv[tid] = c0[b * 128 + tid];
  }
  if (tid < 112) maskI[tid] = 0;
  const float base0 = bi[2 * tid] + bh[2 * tid];
  const float base1 = bi[2 * tid + 1] + bh[2 * tid + 1];
  const float gv0 = gv[lane], gv1 = gv[lane + 64];
  const float pv0 = pv[lane], pv1 = pv[lane + 64];
  const float2* Wi2 = (const float2*)(ws + OFF_WIT);
  const float2* Wh2 = (const float2*)(ws + OFF_WHT);
  const float* gWqT = ws + OFF_GWQT;
  const float* pWqT = ws + OFF_PWQT;
  __syncthreads();

  for (int t = 0; t < 100; t++) {
    // ---- stage 1: gates = x@Wi.T + bi + h@Wh.T + bh (j = 2*tid, 2*tid+1) ----
    float a0 = base0, a1 = base1;
    for (int k = 0; k < 128; k++) {
      float xk = xv[k], hk = hv[k];
      float2 wi = Wi2[k * 256 + tid];
      float2 wh = Wh2[k * 256 + tid];
      a0 += wi.x * xk + wh.x * hk;
      a1 += wi.y * xk + wh.y * hk;
    }
    gates[2 * tid] = a0;
    gates[2 * tid + 1] = a1;
    __syncthreads();

    // ---- stage 2: LSTM cell ----
    if (tid < 128) {
      float ii = 1.f / (1.f + expf(-gates[tid]));
      float ff = 1.f / (1.f + expf(-gates[128 + tid]));
      float gg = tanhf(gates[256 + tid]);
      float oo = 1.f / (1.f + expf(-gates[384 + tid]));
      float cy = ff * cv[tid] + ii * gg;
      float hy = oo * tanhf(cy);
      cv[tid] = cy;
      hv[tid] = hy;
    }
    __syncthreads();

    // ---- stage 3: q = hy @ gWq.T + gbq ----
    if (tid < 128) {
      float acc = gbq[tid];
      for (int k = 0; k < 128; k++) acc += gWqT[k * 128 + tid] * hv[k];
      qv[tid] = acc;
    }
    __syncthreads();

    // ---- stage 4: u_g[s] = sum_h gv[h] * tanh(q[h] + eg[s][h]), masked ----
    for (int s = wid; s < 100; s += 4) {
      float t0 = tanhf(qv[lane] + eg[s * 128 + lane]);
      float t1 = tanhf(qv[lane + 64] + eg[s * 128 + lane + 64]);
      float part = gv0 * t0 + gv1 * t1;
#pragma unroll
      for (int off = 32; off >= 1; off >>= 1) part += __shfl_xor(part, off);
      if (lane == 0) uu[s] = maskI[s] ? -INFINITY : part;
    }
    __syncthreads();

    // ---- stage 5: softmax over uu -> aa ----
    if (wid == 0) {
      float v0 = (lane < 100) ? uu[lane] : -INFINITY;
      float v1 = (lane < 36) ? uu[lane + 64] : -INFINITY;
      float m = fmaxf(v0, v1);
#pragma unroll
      for (int off = 32; off >= 1; off >>= 1) m = fmaxf(m, __shfl_xor(m, off));
      float e0 = (lane < 100) ? expf(v0 - m) : 0.f;
      float e1 = (lane < 36) ? expf(v1 - m) : 0.f;
      float ssum = e0 + e1;
#pragma unroll
      for (int off = 32; off >= 1; off >>= 1) ssum += __shfl_xor(ssum, off);
      if (lane < 100) aa[lane] = e0 / ssum;
      if (lane < 36) aa[lane + 64] = e1 / ssum;
    }
    __syncthreads();

    // ---- stage 6: gl[h] = sum_s eg[s][h] * aa[s] ----
    if (tid < 128) {
      float acc = 0.f;
      for (int s = 0; s < 100; s++) acc += aa[s] * eg[s * 128 + tid];
      glv[tid] = acc;
    }
    __syncthreads();

    // ---- stage 7: q2 = gl @ pWq.T + pbq ----
    if (tid < 128) {
      float acc = pbq[tid];
      for (int k = 0; k < 128; k++) acc += pWqT[k * 128 + tid] * glv[k];
      qv[tid] = acc;
    }
    __syncthreads();

    // ---- stage 8: logits (ep from global — R4-proven) ----
    for (int s = wid; s < 100; s += 4) {
      float t0 = tanhf(qv[lane] + ep[s * 128 + lane]);
      float t1 = tanhf(qv[lane + 64] + ep[s * 128 + lane + 64]);
      float part = pv0 * t0 + pv1 * t1;
#pragma unroll
      for (int off = 32; off >= 1; off >>= 1) part += __shfl_xor(part, off);
      if (lane == 0) lgt[s] = maskI[s] ? -INFINITY : 10.f * tanhf(part);
    }
    __syncthreads();

    // ---- stage 9: softmax -> probs, argmax (first max) ----
    if (wid == 0) {
      float v0 = (lane < 100) ? lgt[lane] : -INFINITY;
      float v1 = (lane < 36) ? lgt[lane + 64] : -INFINITY;
      float m = fmaxf(v0, v1);
#pragma unroll
      for (int off = 32; off >= 1; off >>= 1) m = fmaxf(m, __shfl_xor(m, off));
      float e0 = (lane < 100) ? expf(v0 - m) : 0.f;
      float e1 = (lane < 36) ? expf(v1 - m) : 0.f;
      float ssum = e0 + e1;
#pragma unroll
      for (int off = 32; off >= 1; off >>= 1) ssum += __shfl_xor(ssum, off);
      float p0 = e0 / ssum;
      float p1 = e1 / ssum;
      if (lane < 100) prb[lane] = p0;
      if (lane < 36) prb[lane + 64] = p1;
      float bp;
      int bs;
      if (lane < 100) { bp = p0; bs = lane; } else { bp = -1.f; bs = 1 << 20; }
      if (lane < 36 && p1 > bp) { bp = p1; bs = lane + 64; }
#pragma unroll
      for (int off = 32; off >= 1; off >>= 1) {
        float op = __shfl_xor(bp, off);
        int os = __shfl_xor(bs, off);
        if (op > bp || (op == bp && os < bs)) { bp = op; bs = os; }
      }
      if (lane == 0) {
        selIdx = bs;
        out[OUT_SELS + t * 1024 + b] = (float)bs;
      }
    }
    __syncthreads();

    // ---- stage 10: write probs, gather next input, update mask ----
    if (tid < 100) out[OUT_PROBS + (size_t)t * 102400 + b * 100 + tid] = prb[tid];
    int idx = selIdx;
    if (tid < 128) xv[tid] = emb[((size_t)(idx * 1024 + b)) * 128 + tid];
    if (tid == 0) maskI[idx] = 1;
    __syncthreads();
  }

  if (tid < 128) {
    out[OUT_HX + b * 128 + tid] = hv[tid];
    out[OUT_CX + b * 128 + tid] = cv[tid];
  }
}

// ---------------------------------------------------------------------------
// FALLBACK: round-1 kernel verbatim (eg/ep in LDS), used if ws is too small.
// ---------------------------------------------------------------------------
__global__ __launch_bounds__(256) void decoder_lds(
    const float* __restrict__ dec, const float* __restrict__ emb,
    const float* __restrict__ h0, const float* __restrict__ c0,
    const float* __restrict__ ctx,
    const float* __restrict__ bi, const float* __restrict__ bh,
    const float* __restrict__ gbq, const float* __restrict__ gv,
    const float* __restrict__ pbq, const float* __restrict__ pv,
    const float* __restrict__ gbr, const float* __restrict__ pbr,
    const float* __restrict__ ws, float* __restrict__ out) {
  __shared__ float eg[12800];
  __shared__ float ep[12800];
  __shared__ float xv[128], hv[128], cv[128];
  __shared__ float gates[512];
  __shared__ float qv[128], glv[128];
  __shared__ float uu[112], aa[112], lgt[112], prb[112];
  __shared__ float ctxtile[800];
  __shared__ int maskI[112];
  __shared__ int selIdx;

  const int tid = threadIdx.x;
  const int lane = tid & 63;
  const int wid = tid >> 6;
  const int b = blockIdx.x;

  {
    const int h = tid & 127;
    const int shalf = tid >> 7;
    const float* gWrT = ws + OFF_GWRT;
    const float* pWrT = ws + OFF_PWRT;
    float ag[50], ap[50];
    const float bgv = gbr[h], bpv = pbr[h];
#pragma unroll
    for (int i = 0; i < 50; i++) { ag[i] = bgv; ap[i] = bpv; }
    for (int kb = 0; kb < 128; kb += 8) {
      __syncthreads();
      for (int idx = tid; idx < 800; idx += 256) {
        int kk = idx / 100;
        int s = idx - kk * 100;
        ctxtile[idx] = ctx[((size_t)(s * 128 + kb + kk)) * 1024 + b];
      }
      __syncthreads();
      for (int kk = 0; kk < 8; kk++) {
        int k = kb + kk;
        float wg = gWrT[k * 128 + h];
        float wp = pWrT[k * 128 + h];
        const float* cc = ctxtile + kk * 100 + shalf * 50;
#pragma unroll
        for (int i = 0; i < 50; i++) {
          float cva = cc[i];
          ag[i] += wg * cva;
          ap[i] += wp * cva;
        }
      }
    }
#pragma unroll
    for (int i = 0; i < 50; i++) {
      int s = shalf * 50 + i;
      eg[s * 128 + h] = ag[i];
      ep[s * 128 + h] = ap[i];
    }
  }

  if (tid < 128) {
    xv[tid] = dec[b * 128 + tid];
    hv[tid] = h0[b * 128 + tid];
    cv[tid] = c0[b * 128 + tid];
  }
  if (tid < 112) maskI[tid] = 0;
  const float base0 = bi[2 * tid] + bh[2 * tid];
  const float base1 = bi[2 * tid + 1] + bh[2 * tid + 1];
  const float gv0 = gv[lane], gv1 = gv[lane + 64];
  const float pv0 = pv[lane], pv1 = pv[lane + 64];
  const float2* Wi2 = (const float2*)(ws + OFF_WIT);
  const float2* Wh2 = (const float2*)(ws + OFF_WHT);
  const float* gWqT = ws + OFF_GWQT;
  const float* pWqT = ws + OFF_PWQT;
  __syncthreads();

  for (int t = 0; t < 100; t++) {
    float a0 = base0, a1 = base1;
    for (int k = 0; k < 128; k++) {
      float xk = xv[k], hk = hv[k];
      float2 wi = Wi2[k * 256 + tid];
      float2 wh = Wh2[k * 256 + tid];
      a0 += wi.x * xk + wh.x * hk;
      a1 += wi.y * xk + wh.y * hk;
    }
    gates[2 * tid] = a0;
    gates[2 * tid + 1] = a1;
    __syncthreads();

    if (tid < 128) {
      float ii = 1.f / (1.f + expf(-gates[tid]));
      float ff = 1.f / (1.f + expf(-gates[128 + tid]));
      float gg = tanhf(gates[256 + tid]);
      float oo = 1.f / (1.f + expf(-gates[384 + tid]));
      float cy = ff * cv[tid] + ii * gg;
      float hy = oo * tanhf(cy);
      cv[tid] = cy;
      hv[tid] = hy;
    }
    __syncthreads();

    if (tid < 128) {
      float acc = gbq[tid];
      for (int k = 0; k < 128; k++) acc += gWqT[k * 128 + tid] * hv[k];
      qv[tid] = acc;
    }
    __syncthreads();

    for (int s = wid; s < 100; s += 4) {
      float t0 = tanhf(qv[lane] + eg[s * 128 + lane]);
      float t1 = tanhf(qv[lane + 64] + eg[s * 128 + lane + 64]);
      float part = gv0 * t0 + gv1 * t1;
#pragma unroll
      for (int off = 32; off >= 1; off >>= 1) part += __shfl_xor(part, off);
      if (lane == 0) uu[s] = maskI[s] ? -INFINITY : part;
    }
    __syncthreads();

    if (wid == 0) {
      float v0 = (lane < 100) ? uu[lane] : -INFINITY;
      float v1 = (lane < 36) ? uu[lane + 64] : -INFINITY;
      float m = fmaxf(v0, v1);
#pragma unroll
      for (int off = 32; off >= 1; off >>= 1) m = fmaxf(m, __shfl_xor(m, off));
      float e0 = (lane < 100) ? expf(v0 - m) : 0.f;
      float e1 = (lane < 36) ? expf(v1 - m) : 0.f;
      float ssum = e0 + e1;
#pragma unroll
      for (int off = 32; off >= 1; off >>= 1) ssum += __shfl_xor(ssum, off);
      if (lane < 100) aa[lane] = e0 / ssum;
      if (lane < 36) aa[lane + 64] = e1 / ssum;
    }
    __syncthreads();

    if (tid < 128) {
      float acc = 0.f;
      for (int s = 0; s < 100; s++) acc += aa[s] * eg[s * 128 + tid];
      glv[tid] = acc;
    }
    __syncthreads();

    if (tid < 128) {
      float acc = pbq[tid];
      for (int k = 0; k < 128; k++) acc += pWqT[k * 128 + tid] * glv[k];
      qv[tid] = acc;
    }
    __syncthreads();

    for (int s = wid; s < 100; s += 4) {
      float t0 = tanhf(qv[lane] + ep[s * 128 + lane]);
      float t1 = tanhf(qv[lane + 64] + ep[s * 128 + lane + 64]);
      float part = pv0 * t0 + pv1 * t1;
#pragma unroll
      for (int off = 32; off >= 1; off >>= 1) part += __shfl_xor(part, off);
      if (lane == 0) lgt[s] = maskI[s] ? -INFINITY : 10.f * tanhf(part);
    }
    __syncthreads();

    if (wid == 0) {
      float v0 = (lane < 100) ? lgt[lane] : -INFINITY;
      float v1 = (lane < 36) ? lgt[lane + 64] : -INFINITY;
      float m = fmaxf(v0, v1);
#pragma unroll
      for (int off = 32; off >= 1; off >>= 1) m = fmaxf(m, __shfl_xor(m, off));
      float e0 = (lane < 100) ? expf(v0 - m) : 0.f;
      float e1 = (lane < 36) ? expf(v1 - m) : 0.f;
      float ssum = e0 + e1;
#pragma unroll
      for (int off = 32; off >= 1; off >>= 1) ssum += __shfl_xor(ssum, off);
      float p0 = e0 / ssum;
      float p1 = e1 / ssum;
      if (lane < 100) prb[lane] = p0;
      if (lane < 36) prb[lane + 64] = p1;
      float bp;
      int bs;
      if (lane < 100) { bp = p0; bs = lane; } else { bp = -1.f; bs = 1 << 20; }
      if (lane < 36 && p1 > bp) { bp = p1; bs = lane + 64; }
#pragma unroll
      for (int off = 32; off >= 1; off >>= 1) {
        float op = __shfl_xor(bp, off);
        int os = __shfl_xor(bs, off);
        if (op > bp || (op == bp && os < bs)) { bp = op; bs = os; }
      }
      if (lane == 0) {
        selIdx = bs;
        out[OUT_SELS + t * 1024 + b] = (float)bs;
      }
    }
    __syncthreads();

    if (tid < 100) out[OUT_PROBS + (size_t)t * 102400 + b * 100 + tid] = prb[tid];
    int idx = selIdx;
    if (tid < 128) xv[tid] = emb[((size_t)(idx * 1024 + b)) * 128 + tid];
    if (tid == 0) maskI[idx] = 1;
    __syncthreads();
  }

  if (tid < 128) {
    out[OUT_HX + b * 128 + tid] = hv[tid];
    out[OUT_CX + b * 128 + tid] = cv[tid];
  }
}

extern "C" void kernel_launch(void* const* d_in, const int* in_sizes, int n_in,
                              void* d_out, int out_size, void* d_ws, size_t ws_size,
                              hipStream_t stream) {
  (void)in_sizes; (void)n_in; (void)out_size;
  const float* dec = (const float*)d_in[0];
  const float* emb = (const float*)d_in[1];
  const float* h0  = (const float*)d_in[2];
  const float* c0  = (const float*)d_in[3];
  const float* ctx = (const float*)d_in[4];
  const float* Wi  = (const float*)d_in[5];
  const float* bi  = (const float*)d_in[6];
  const float* Wh  = (const float*)d_in[7];
  const float* bh  = (const float*)d_in[8];
  const float* gWq = (const float*)d_in[9];
  const float* gbq = (const float*)d_in[10];
  const float* gWr = (const float*)d_in[11];
  const float* gbr = (const float*)d_in[12];
  const float* gv  = (const float*)d_in[13];
  const float* pWq = (const float*)d_in[14];
  const float* pbq = (const float*)d_in[15];
  const float* pWr = (const float*)d_in[16];
  const float* pbr = (const float*)d_in[17];
  const float* pv  = (const float*)d_in[18];
  float* ws = (float*)d_ws;
  float* out = (float*)d_out;

  hipLaunchKernelGGL(transpose_k, dim3(256), dim3(256), 0, stream,
                     Wi, Wh, gWq, pWq, gWr, pWr, ws);

  const size_t need_bytes = (size_t)(OFF_EP + 13107200ull) * 4ull;  // ~105.6 MB
  if (ws_size >= need_bytes) {
    float* egs = ws + OFF_EG;
    float* eps = ws + OFF_EP;
    hipLaunchKernelGGL(precompute_e, dim3(1024), dim3(256), 0, stream,
                       ctx, gbr, pbr, ws, egs, eps);
    hipLaunchKernelGGL(decoder_fast, dim3(1024), dim3(256), 0, stream,
                       dec, emb, h0, c0, bi, bh, gbq, gv, pbq, pv,
                       ws, egs, eps, out);
  } else {
    hipLaunchKernelGGL(decoder_lds, dim3(1024), dim3(256), 0, stream,
                       dec, emb, h0, c0, ctx, bi, bh, gbq, gv, pbq, pv, gbr, pbr,
                       ws, out);
  }
}